// Round 1
// baseline (17467.201 us; speedup 1.0000x reference)
//
#include <hip/hip_runtime.h>
#include <hip/hip_cooperative_groups.h>
#include <stdint.h>

namespace cg = cooperative_groups;

// ---- problem constants ----
#define IDIM   40
#define HID    256
#define GATES  1024           // 4*HID
#define KTOT   296            // IDIM + HID
#define TSTEPS 256
#define BATCH  1024
#define ODIM   12
#define NNOISE (KTOT*GATES)   // 303104
#define NIH    (IDIM*GATES)   // 40960

// JAX RNG mode: 1 = threefry_partitionable (modern default), 0 = legacy block layout
#define JAX_PARTITIONABLE 1

// ---- ws layout (byte offsets); total ~4.5 MB ----
#define WS_WMAX 0              // 2 floats (atomic max, memset 0)
#define WS_KEYS 64             // 256*4 u32  (k1a,k1b,k2a,k2b per step)
#define WS_BIAS 4160           // 1024 f32
#define WS_QW   8256           // 303104 f32
#define WS_HBUF 1220672        // 2 * 1024*256 ushort(bf16); hbuf[0] memset 0
#define WS_WN   2269248        // 2 * 303104 f32 (noisy weights, double buffered)
#define HBUF_N  (BATCH*HID)

// ======================= threefry2x32 (exact JAX) =======================
__device__ __forceinline__ uint32_t rotl32(uint32_t x, int r){ return (x<<r)|(x>>(32-r)); }

__device__ __forceinline__ void tf2x32(uint32_t k0, uint32_t k1, uint32_t c0, uint32_t c1,
                                       uint32_t &o0, uint32_t &o1){
  uint32_t ks2 = k0 ^ k1 ^ 0x1BD11BDAu;
  uint32_t x0 = c0 + k0, x1 = c1 + k1;
#define R4(a,b,c,d) x0+=x1; x1=rotl32(x1,a); x1^=x0; x0+=x1; x1=rotl32(x1,b); x1^=x0; \
                    x0+=x1; x1=rotl32(x1,c); x1^=x0; x0+=x1; x1=rotl32(x1,d); x1^=x0;
  R4(13,15,26,6)  x0+=k1;  x1+=ks2+1u;
  R4(17,29,16,24) x0+=ks2; x1+=k0+2u;
  R4(13,15,26,6)  x0+=k0;  x1+=k1+3u;
  R4(17,29,16,24) x0+=k1;  x1+=ks2+4u;
  R4(13,15,26,6)  x0+=ks2; x1+=k0+5u;
#undef R4
  o0=x0; o1=x1;
}

// ======================= XLA-faithful math =======================
// XLA ErfInv f32 (Giles polynomial), no FMA contraction
__device__ __forceinline__ float erfinv_xla(float x){
  float w = -log1pf(-__fmul_rn(x,x));
  float p;
  if (w < 5.0f){
    w = __fsub_rn(w, 2.5f);
    p = 2.81022636e-08f;
    p = __fadd_rn(__fmul_rn(p,w),  3.43273939e-07f);
    p = __fadd_rn(__fmul_rn(p,w), -3.5233877e-06f);
    p = __fadd_rn(__fmul_rn(p,w), -4.39150654e-06f);
    p = __fadd_rn(__fmul_rn(p,w),  0.00021858087f);
    p = __fadd_rn(__fmul_rn(p,w), -0.00125372503f);
    p = __fadd_rn(__fmul_rn(p,w), -0.00417768164f);
    p = __fadd_rn(__fmul_rn(p,w),  0.246640727f);
    p = __fadd_rn(__fmul_rn(p,w),  1.50140941f);
  } else {
    w = __fsub_rn(sqrtf(w), 3.0f);
    p = -0.000200214257f;
    p = __fadd_rn(__fmul_rn(p,w),  0.000100950558f);
    p = __fadd_rn(__fmul_rn(p,w),  0.00134934322f);
    p = __fadd_rn(__fmul_rn(p,w), -0.00367342844f);
    p = __fadd_rn(__fmul_rn(p,w),  0.00573950773f);
    p = __fadd_rn(__fmul_rn(p,w), -0.0076224613f);
    p = __fadd_rn(__fmul_rn(p,w),  0.00943887047f);
    p = __fadd_rn(__fmul_rn(p,w),  1.00167406f);
    p = __fadd_rn(__fmul_rn(p,w),  2.83297682f);
  }
  return __fmul_rn(p, x);
}

// XLA EmitFastTanh: |x|<0.0004 -> x ; clamp to [-9,9]; rational poly (no FMA)
__device__ __forceinline__ float tanh_xla(float x){
  float xc = fminf(fmaxf(x, -9.0f), 9.0f);
  float x2 = __fmul_rn(xc, xc);
  float p = -2.76076847742355e-16f;
  p = __fadd_rn(__fmul_rn(p,x2),  2.00018790482477e-13f);
  p = __fadd_rn(__fmul_rn(p,x2), -8.60467152213735e-11f);
  p = __fadd_rn(__fmul_rn(p,x2),  5.12229709037114e-08f);
  p = __fadd_rn(__fmul_rn(p,x2),  1.48572235717979e-05f);
  p = __fadd_rn(__fmul_rn(p,x2),  6.37261928875436e-04f);
  p = __fadd_rn(__fmul_rn(p,x2),  4.89352455891786e-03f);
  float num = __fmul_rn(xc, p);
  float q = 1.19825839466702e-06f;
  q = __fadd_rn(__fmul_rn(q,x2),  1.18534705686654e-04f);
  q = __fadd_rn(__fmul_rn(q,x2),  2.26843463243900e-03f);
  q = __fadd_rn(__fmul_rn(q,x2),  4.89352518554385e-03f);
  float r = __fdiv_rn(num, q);
  return (fabsf(x) < 0.0004f) ? x : r;
}

// XLA logistic expansion: 0.5 + 0.5*tanh(0.5*x)
__device__ __forceinline__ float sigmoid_xla(float x){
  return __fadd_rn(0.5f, __fmul_rn(0.5f, tanh_xla(__fmul_rn(0.5f, x))));
}

// quant_clip: y = round(clip(x,0,1)*s)/s ; return x + (y - x)   (faithful op order)
__device__ __forceinline__ float qclip(float x, float s, float inv){
  float c = fminf(fmaxf(x, 0.0f), 1.0f);
  float y = __fmul_rn(rintf(__fmul_rn(c, s)), inv);
  return __fadd_rn(x, __fsub_rn(y, x));
}

// bits -> N(0,1) exactly as jax.random.normal (f32)
__device__ __forceinline__ float bits_to_normal(uint32_t bits){
  float f = __fsub_rn(__uint_as_float((bits>>9) | 0x3F800000u), 1.0f);
  const float LO = __uint_as_float(0xBF7FFFFFu);         // nextafter(-1,0)
  float u = fmaxf(LO, __fadd_rn(__fmul_rn(f, 2.0f), LO)); // (hi-lo) rounds to 2.0 exactly
  return __fmul_rn(__uint_as_float(0x3FB504F3u), erfinv_xla(u)); // sqrt(2)*erfinv(u)
}

// generate noisy weights for one step into dst[NNOISE]
__device__ __forceinline__ void gen_noise_step(const uint32_t* kk, const float* qw,
                                               float wmih, float wmhh, float* dst, int gid){
  for (int idx = gid; idx < NNOISE; idx += 65536){
    bool ih = idx < NIH;
    uint32_t key0 = ih ? kk[0] : kk[2];
    uint32_t key1 = ih ? kk[1] : kk[3];
    uint32_t li   = ih ? (uint32_t)idx : (uint32_t)(idx - NIH);
    uint32_t bits;
#if JAX_PARTITIONABLE
    uint32_t a,b; tf2x32(key0,key1, 0u, li, a,b); bits = a ^ b;
#else
    uint32_t n = ih ? (uint32_t)NIH : (uint32_t)(NNOISE-NIH);
    uint32_t half = n >> 1;
    uint32_t a,b;
    if (li < half){ tf2x32(key0,key1, li, li+half, a,b); bits = a; }
    else          { tf2x32(key0,key1, li-half, li, a,b); bits = b; }
#endif
    float nv = bits_to_normal(bits);
    float noise = __fmul_rn(__fmul_rn(nv, ih ? wmih : wmhh), 0.1f);
    dst[idx] = __fadd_rn(qw[idx], noise);
  }
}

// ======================= prep kernel =======================
__global__ void __launch_bounds__(256)
kws_prep(const float* __restrict__ w_ih, const float* __restrict__ w_hh,
         const float* __restrict__ b_ih, const float* __restrict__ b_hh,
         float* __restrict__ ws){
  const int gtid = blockIdx.x*256 + threadIdx.x;
  const int nth  = gridDim.x*256;
  float* wmax = ws + WS_WMAX/4;
  uint32_t* keys = (uint32_t*)((char*)ws + WS_KEYS);
  float* bias = ws + WS_BIAS/4;
  float* qw   = ws + WS_QW/4;

  // quantized transposed weights, combined [KTOT][GATES]
  for (int idx = gtid; idx < NNOISE; idx += nth){
    int r = idx >> 10, j = idx & 1023;
    float w = (r < IDIM) ? w_ih[j*IDIM + r] : w_hh[j*HID + (r-IDIM)];
    qw[idx] = qclip(w, 128.0f, 0.0078125f);
  }
  // combined bias (qb_ih + qb_hh)
  for (int j = gtid; j < GATES; j += nth)
    bias[j] = __fadd_rn(qclip(b_ih[j],128.0f,0.0078125f), qclip(b_hh[j],128.0f,0.0078125f));
  // per-step RNG keys: keyt = fold_in(key(42), t); k1,k2 = split(keyt)
  for (int t = gtid; t < TSTEPS; t += nth){
    uint32_t ka,kb, k1a,k1b,k2a,k2b;
    tf2x32(0u, 42u, 0u, (uint32_t)t, ka, kb);
#if JAX_PARTITIONABLE
    tf2x32(ka,kb, 0u,0u, k1a,k1b);
    tf2x32(ka,kb, 0u,1u, k2a,k2b);
#else
    uint32_t e1a,e1b,e2a,e2b;
    tf2x32(ka,kb, 0u,2u, e1a,e1b);
    tf2x32(ka,kb, 1u,3u, e2a,e2b);
    k1a=e1a; k1b=e2a; k2a=e1b; k2b=e2b;
#endif
    keys[t*4+0]=k1a; keys[t*4+1]=k1b; keys[t*4+2]=k2a; keys[t*4+3]=k2b;
  }
  // wmax (raw weights, exact max)
  float m1 = -1e30f, m2 = -1e30f;
  for (int i = gtid; i < GATES*IDIM; i += nth) m1 = fmaxf(m1, w_ih[i]);
  for (int i = gtid; i < GATES*HID;  i += nth) m2 = fmaxf(m2, w_hh[i]);
  for (int off = 32; off; off >>= 1){
    m1 = fmaxf(m1, __shfl_down(m1, off));
    m2 = fmaxf(m2, __shfl_down(m2, off));
  }
  if ((threadIdx.x & 63) == 0){
    if (m1 > 0.f) atomicMax((int*)&wmax[0], __float_as_int(m1));  // positive floats order as ints
    if (m2 > 0.f) atomicMax((int*)&wmax[1], __float_as_int(m2));
  }
}

// ======================= cooperative LSTM kernel =======================
// grid 256 wgs x 256 thr; wg = (batch tile 64) x (hidden tile 16) -> 64 gate cols (4 quarters x 16)
__global__ void __launch_bounds__(256)
kws_lstm_coop(const float* __restrict__ inputs, const float* __restrict__ out_w,
              const float* __restrict__ out_b, float* __restrict__ out,
              float* __restrict__ ws){
  cg::grid_group grid = cg::this_grid();
  const int tid = threadIdx.x;
  const int wg  = blockIdx.x;
  const int bi  = wg >> 4;
  const int hj  = wg & 15;
  const int b0  = bi * 64;
  const int k0  = hj * 16;
  const int gid = (wg << 8) | tid;

  const float* wmax = ws + WS_WMAX/4;
  const uint32_t* keys = (const uint32_t*)((char*)ws + WS_KEYS);
  const float* bias = ws + WS_BIAS/4;
  const float* qw   = ws + WS_QW/4;
  unsigned short* hbuf = (unsigned short*)((char*)ws + WS_HBUF);
  float* wn = (float*)((char*)ws + WS_WN);

  // LDS: actX f32[40][68] @0 (10880B) | actH bf16[256][68] @10880 (34816B) | wch f32[64][68] @45696 (17408B)
  // gates f32[64][68] unions over actX/actH after GEMM.
  __shared__ __align__(16) char smem[63104];
  float* actX = (float*)smem;
  unsigned short* actH = (unsigned short*)(smem + 10880);
  float* wch = (float*)(smem + 45696);
  float* gsm = (float*)smem;

  const float wmih = wmax[0], wmhh = wmax[1];
  const int tn = tid & 15, tm = tid >> 4;
  const int um = tid >> 2, ukbase = (tid & 3) * 4;

  float c_reg[4] = {0.f,0.f,0.f,0.f};

  // prologue: noisy weights for t=0
  gen_noise_step(keys + 0, qw, wmih, wmhh, wn, gid);
  grid.sync();

  for (int t = 0; t < TSTEPS; ++t){
    const float* wcur = wn + (size_t)(t & 1) * NNOISE;
    float* wnxt = wn + (size_t)((t + 1) & 1) * NNOISE;
    const unsigned short* hcur = hbuf + (size_t)(t & 1) * HBUF_N;
    unsigned short* hnxt = hbuf + (size_t)((t + 1) & 1) * HBUF_N;

    // A) pipeline: generate noisy weights for t+1
    if (t + 1 < TSTEPS)
      gen_noise_step(keys + (t+1)*4, qw, wmih, wmhh, wnxt, gid);

    // B) stage activations: x_t quantized (f32) + h_t (bf16, exact)
    for (int e = tid; e < 64*IDIM; e += 256){
      int m = e / IDIM, kx = e - m*IDIM;
      float x = inputs[((size_t)t*BATCH + b0 + m)*IDIM + kx];
      actX[kx*68 + m] = qclip(x, 128.0f, 0.0078125f);
    }
    for (int e = tid; e < (64*HID)/4; e += 256){
      int m = e >> 6, k4 = (e & 63) * 4;
      const ushort4 hv = *(const ushort4*)&hcur[(size_t)(b0+m)*HID + k4];
      actH[(k4+0)*68 + m] = hv.x;
      actH[(k4+1)*68 + m] = hv.y;
      actH[(k4+2)*68 + m] = hv.z;
      actH[(k4+3)*68 + m] = hv.w;
    }
    __syncthreads();

    // C) GEMM: gates[64 x 64cols], K staged in chunks {40, 64,64,64,64}
    float acc[4][4];
    #pragma unroll
    for (int a=0;a<4;++a){ acc[a][0]=0.f; acc[a][1]=0.f; acc[a][2]=0.f; acc[a][3]=0.f; }

    #pragma unroll 1
    for (int ci = 0; ci < 5; ++ci){
      const int c0  = (ci == 0) ? 0 : (40 + 64*(ci-1));
      const int csz = (ci == 0) ? 40 : 64;
      __syncthreads();
      for (int e = tid; e < csz*64; e += 256){
        int kr = e >> 6, n = e & 63;
        int col = ((n >> 4) << 8) + k0 + (n & 15);
        wch[kr*68 + n] = wcur[(size_t)(c0 + kr)*GATES + col];
      }
      __syncthreads();
      if (ci == 0){
        #pragma unroll 4
        for (int k = 0; k < 40; ++k){
          const float4 wv = *(const float4*)&wch[k*68 + 4*tn];
          const float4 av = *(const float4*)&actX[k*68 + 4*tm];
          float a4[4] = {av.x, av.y, av.z, av.w};
          #pragma unroll
          for (int rm=0;rm<4;++rm){
            acc[rm][0] = fmaf(a4[rm], wv.x, acc[rm][0]);
            acc[rm][1] = fmaf(a4[rm], wv.y, acc[rm][1]);
            acc[rm][2] = fmaf(a4[rm], wv.z, acc[rm][2]);
            acc[rm][3] = fmaf(a4[rm], wv.w, acc[rm][3]);
          }
        }
      } else {
        const int hb = c0 - 40;
        #pragma unroll 4
        for (int k2 = 0; k2 < 64; ++k2){
          const float4 wv = *(const float4*)&wch[k2*68 + 4*tn];
          const ushort4 hv = *(const ushort4*)&actH[(hb + k2)*68 + 4*tm];
          float a4[4] = { __uint_as_float((uint32_t)hv.x << 16),
                          __uint_as_float((uint32_t)hv.y << 16),
                          __uint_as_float((uint32_t)hv.z << 16),
                          __uint_as_float((uint32_t)hv.w << 16) };
          #pragma unroll
          for (int rm=0;rm<4;++rm){
            acc[rm][0] = fmaf(a4[rm], wv.x, acc[rm][0]);
            acc[rm][1] = fmaf(a4[rm], wv.y, acc[rm][1]);
            acc[rm][2] = fmaf(a4[rm], wv.z, acc[rm][2]);
            acc[rm][3] = fmaf(a4[rm], wv.w, acc[rm][3]);
          }
        }
      }
    }
    __syncthreads();

    // D) gates + bias -> LDS (union region)
    #pragma unroll
    for (int rn = 0; rn < 4; ++rn){
      int n = 4*tn + rn;
      int col = ((n >> 4) << 8) + k0 + (n & 15);
      float bb = bias[col];
      #pragma unroll
      for (int rm = 0; rm < 4; ++rm)
        gsm[(4*tm + rm)*68 + n] = __fadd_rn(acc[rm][rn], bb);
    }
    __syncthreads();

    // E) state update (thread owns rows um, hidden cols k0+ukbase..+3)
    unsigned short us[4];
    #pragma unroll
    for (int j = 0; j < 4; ++j){
      int kk = ukbase + j;
      float gi = gsm[um*68 + kk];
      float gf = gsm[um*68 + 16 + kk];
      float gg = gsm[um*68 + 32 + kk];
      float go = gsm[um*68 + 48 + kk];
      float i_ = qclip(sigmoid_xla(gi), 256.0f, 0.00390625f);
      float f_ = qclip(sigmoid_xla(gf), 256.0f, 0.00390625f);
      float g_ = qclip(tanh_xla(gg),    128.0f, 0.0078125f);
      float o_ = qclip(sigmoid_xla(go), 256.0f, 0.00390625f);
      float cpre = __fadd_rn(__fmul_rn(f_, c_reg[j]), __fmul_rn(i_, g_));
      float cy = qclip(cpre, 128.0f, 0.0078125f);
      float hy = qclip(__fmul_rn(o_, tanh_xla(cy)), 128.0f, 0.0078125f);
      c_reg[j] = cy;
      us[j] = (unsigned short)(__float_as_uint(hy) >> 16);  // hy is a multiple of 1/128: exact bf16
    }
    {
      ushort4 hv; hv.x = us[0]; hv.y = us[1]; hv.z = us[2]; hv.w = us[3];
      *(ushort4*)&hnxt[(size_t)(b0 + um)*HID + k0 + ukbase] = hv;
    }
    grid.sync();
  }

  // epilogue: fc = h_T @ out_w.T + out_b ; out = qclip(sigmoid(fc), 256)
  const unsigned short* hf = hbuf;   // final h lives in buffer (TSTEPS & 1) == 0
  if (gid < BATCH*ODIM){
    int b = gid / ODIM, o = gid - b*ODIM;
    float s = 0.f;
    for (int k = 0; k < HID; ++k){
      float h = __uint_as_float((uint32_t)hf[(size_t)b*HID + k] << 16);
      s = fmaf(h, out_w[o*HID + k], s);
    }
    s = __fadd_rn(s, out_b[o]);
    out[b*ODIM + o] = qclip(sigmoid_xla(s), 256.0f, 0.00390625f);
  }
}

// ======================= launch =======================
extern "C" void kernel_launch(void* const* d_in, const int* in_sizes, int n_in,
                              void* d_out, int out_size, void* d_ws, size_t ws_size,
                              hipStream_t stream){
  const float* inputs = (const float*)d_in[0];
  const float* w_ih   = (const float*)d_in[1];
  const float* w_hh   = (const float*)d_in[2];
  const float* b_ih   = (const float*)d_in[3];
  const float* b_hh   = (const float*)d_in[4];
  const float* out_w  = (const float*)d_in[5];
  const float* out_b  = (const float*)d_in[6];
  float* out = (float*)d_out;
  float* ws  = (float*)d_ws;

  // zero wmax slots + h0 buffer
  hipMemsetAsync(d_ws, 0, 8, stream);
  hipMemsetAsync((char*)d_ws + WS_HBUF, 0, HBUF_N*sizeof(unsigned short), stream);

  kws_prep<<<dim3(256), dim3(256), 0, stream>>>(w_ih, w_hh, b_ih, b_hh, ws);

  void* args[] = { (void*)&inputs, (void*)&out_w, (void*)&out_b, (void*)&out, (void*)&ws };
  hipLaunchCooperativeKernel((const void*)kws_lstm_coop, dim3(256), dim3(256),
                             args, 0, stream);
}

// Round 4
// 14268.925 us; speedup vs baseline: 1.2241x; 1.2241x over previous
//
#include <hip/hip_runtime.h>
#include <hip/hip_cooperative_groups.h>
#include <stdint.h>

namespace cg = cooperative_groups;

// ---- problem constants ----
#define IDIM   40
#define HID    256
#define GATES  1024           // 4*HID
#define KTOT   296            // IDIM + HID
#define TSTEPS 256
#define BATCH  1024
#define ODIM   12
#define NNOISE (KTOT*GATES)   // 303104
#define NIH    (IDIM*GATES)   // 40960
#define NTHR_TOTAL 131072     // 256 WGs x 512 thr

// ---- ws layout (byte offsets); total ~4.7 MB ----
#define WS_WMAX 0              // 2 floats (atomic max, memset 0)
#define WS_KEYS 64             // 256*4 u32
#define WS_BIAS 4160           // 1024 f32
#define WS_QW   8256           // 303104 f32  [KTOT][1024]
#define WS_HT   1220672        // 2 * 256*1024 u16 (bf16, [hid][batch]); buf0 memset 0
#define WS_WN   2269248        // 2 * 303104 f32 (noisy weights, double buffered)
#define HT_N    (HID*BATCH)    // 262144 u16 per buffer

// ======================= threefry2x32 (exact JAX) =======================
__device__ __forceinline__ uint32_t rotl32(uint32_t x, int r){ return (x<<r)|(x>>(32-r)); }

__device__ __forceinline__ void tf2x32(uint32_t k0, uint32_t k1, uint32_t c0, uint32_t c1,
                                       uint32_t &o0, uint32_t &o1){
  uint32_t ks2 = k0 ^ k1 ^ 0x1BD11BDAu;
  uint32_t x0 = c0 + k0, x1 = c1 + k1;
#define R4(a,b,c,d) x0+=x1; x1=rotl32(x1,a); x1^=x0; x0+=x1; x1=rotl32(x1,b); x1^=x0; \
                    x0+=x1; x1=rotl32(x1,c); x1^=x0; x0+=x1; x1=rotl32(x1,d); x1^=x0;
  R4(13,15,26,6)  x0+=k1;  x1+=ks2+1u;
  R4(17,29,16,24) x0+=ks2; x1+=k0+2u;
  R4(13,15,26,6)  x0+=k0;  x1+=k1+3u;
  R4(17,29,16,24) x0+=k1;  x1+=ks2+4u;
  R4(13,15,26,6)  x0+=ks2; x1+=k0+5u;
#undef R4
  o0=x0; o1=x1;
}

// ======================= XLA-faithful math =======================
__device__ __forceinline__ float erfinv_xla(float x){
  float w = -log1pf(-__fmul_rn(x,x));
  float p;
  if (w < 5.0f){
    w = __fsub_rn(w, 2.5f);
    p = 2.81022636e-08f;
    p = __fadd_rn(__fmul_rn(p,w),  3.43273939e-07f);
    p = __fadd_rn(__fmul_rn(p,w), -3.5233877e-06f);
    p = __fadd_rn(__fmul_rn(p,w), -4.39150654e-06f);
    p = __fadd_rn(__fmul_rn(p,w),  0.00021858087f);
    p = __fadd_rn(__fmul_rn(p,w), -0.00125372503f);
    p = __fadd_rn(__fmul_rn(p,w), -0.00417768164f);
    p = __fadd_rn(__fmul_rn(p,w),  0.246640727f);
    p = __fadd_rn(__fmul_rn(p,w),  1.50140941f);
  } else {
    w = __fsub_rn(sqrtf(w), 3.0f);
    p = -0.000200214257f;
    p = __fadd_rn(__fmul_rn(p,w),  0.000100950558f);
    p = __fadd_rn(__fmul_rn(p,w),  0.00134934322f);
    p = __fadd_rn(__fmul_rn(p,w), -0.00367342844f);
    p = __fadd_rn(__fmul_rn(p,w),  0.00573950773f);
    p = __fadd_rn(__fmul_rn(p,w), -0.0076224613f);
    p = __fadd_rn(__fmul_rn(p,w),  0.00943887047f);
    p = __fadd_rn(__fmul_rn(p,w),  1.00167406f);
    p = __fadd_rn(__fmul_rn(p,w),  2.83297682f);
  }
  return __fmul_rn(p, x);
}

__device__ __forceinline__ float tanh_xla(float x){
  float xc = fminf(fmaxf(x, -9.0f), 9.0f);
  float x2 = __fmul_rn(xc, xc);
  float p = -2.76076847742355e-16f;
  p = __fadd_rn(__fmul_rn(p,x2),  2.00018790482477e-13f);
  p = __fadd_rn(__fmul_rn(p,x2), -8.60467152213735e-11f);
  p = __fadd_rn(__fmul_rn(p,x2),  5.12229709037114e-08f);
  p = __fadd_rn(__fmul_rn(p,x2),  1.48572235717979e-05f);
  p = __fadd_rn(__fmul_rn(p,x2),  6.37261928875436e-04f);
  p = __fadd_rn(__fmul_rn(p,x2),  4.89352455891786e-03f);
  float num = __fmul_rn(xc, p);
  float q = 1.19825839466702e-06f;
  q = __fadd_rn(__fmul_rn(q,x2),  1.18534705686654e-04f);
  q = __fadd_rn(__fmul_rn(q,x2),  2.26843463243900e-03f);
  q = __fadd_rn(__fmul_rn(q,x2),  4.89352518554385e-03f);
  float r = __fdiv_rn(num, q);
  return (fabsf(x) < 0.0004f) ? x : r;
}

__device__ __forceinline__ float sigmoid_xla(float x){
  return __fadd_rn(0.5f, __fmul_rn(0.5f, tanh_xla(__fmul_rn(0.5f, x))));
}

__device__ __forceinline__ float qclip(float x, float s, float inv){
  float c = fminf(fmaxf(x, 0.0f), 1.0f);
  float y = __fmul_rn(rintf(__fmul_rn(c, s)), inv);
  return __fadd_rn(x, __fsub_rn(y, x));
}

__device__ __forceinline__ float bits_to_normal(uint32_t bits){
  float f = __fsub_rn(__uint_as_float((bits>>9) | 0x3F800000u), 1.0f);
  const float LO = __uint_as_float(0xBF7FFFFFu);
  float u = fmaxf(LO, __fadd_rn(__fmul_rn(f, 2.0f), LO));
  return __fmul_rn(__uint_as_float(0x3FB504F3u), erfinv_xla(u));
}

__device__ __forceinline__ void gen_noise_step(const uint32_t* kk, const float* qw,
                                               float wmih, float wmhh, float* dst, int gid){
  for (int idx = gid; idx < NNOISE; idx += NTHR_TOTAL){
    bool ih = idx < NIH;
    uint32_t key0 = ih ? kk[0] : kk[2];
    uint32_t key1 = ih ? kk[1] : kk[3];
    uint32_t li   = ih ? (uint32_t)idx : (uint32_t)(idx - NIH);
    uint32_t a,b; tf2x32(key0,key1, 0u, li, a,b);
    uint32_t bits = a ^ b;
    float nv = bits_to_normal(bits);
    float noise = __fmul_rn(__fmul_rn(nv, ih ? wmih : wmhh), 0.1f);
    dst[idx] = __fadd_rn(qw[idx], noise);
  }
}

// ======================= prep kernel =======================
__global__ void __launch_bounds__(256)
kws_prep(const float* __restrict__ w_ih, const float* __restrict__ w_hh,
         const float* __restrict__ b_ih, const float* __restrict__ b_hh,
         float* __restrict__ ws){
  const int gtid = blockIdx.x*256 + threadIdx.x;
  const int nth  = gridDim.x*256;
  float* wmax = ws + WS_WMAX/4;
  uint32_t* keys = (uint32_t*)((char*)ws + WS_KEYS);
  float* bias = ws + WS_BIAS/4;
  float* qw   = ws + WS_QW/4;

  for (int idx = gtid; idx < NNOISE; idx += nth){
    int r = idx >> 10, j = idx & 1023;
    float w = (r < IDIM) ? w_ih[j*IDIM + r] : w_hh[j*HID + (r-IDIM)];
    qw[idx] = qclip(w, 128.0f, 0.0078125f);
  }
  for (int j = gtid; j < GATES; j += nth)
    bias[j] = __fadd_rn(qclip(b_ih[j],128.0f,0.0078125f), qclip(b_hh[j],128.0f,0.0078125f));
  for (int t = gtid; t < TSTEPS; t += nth){
    uint32_t ka,kb, k1a,k1b,k2a,k2b;
    tf2x32(0u, 42u, 0u, (uint32_t)t, ka, kb);
    tf2x32(ka,kb, 0u,0u, k1a,k1b);
    tf2x32(ka,kb, 0u,1u, k2a,k2b);
    keys[t*4+0]=k1a; keys[t*4+1]=k1b; keys[t*4+2]=k2a; keys[t*4+3]=k2b;
  }
  float m1 = -1e30f, m2 = -1e30f;
  for (int i = gtid; i < GATES*IDIM; i += nth) m1 = fmaxf(m1, w_ih[i]);
  for (int i = gtid; i < GATES*HID;  i += nth) m2 = fmaxf(m2, w_hh[i]);
  for (int off = 32; off; off >>= 1){
    m1 = fmaxf(m1, __shfl_down(m1, off));
    m2 = fmaxf(m2, __shfl_down(m2, off));
  }
  if ((threadIdx.x & 63) == 0){
    if (m1 > 0.f) atomicMax((int*)&wmax[0], __float_as_int(m1));
    if (m2 > 0.f) atomicMax((int*)&wmax[1], __float_as_int(m2));
  }
}

// ======================= cooperative LSTM kernel =======================
// grid 256 wgs x 512 thr; wg = (batch tile 64) x (hidden tile 16) -> 64 gate cols
// thread GEMM tile: 2 rows x 4 cols. A staged per chunk straight from global.
__global__ void __launch_bounds__(512)
kws_lstm_coop(const float* __restrict__ inputs, const float* __restrict__ out_w,
              const float* __restrict__ out_b, float* __restrict__ out,
              float* __restrict__ ws){
  cg::grid_group grid = cg::this_grid();
  const int tid = threadIdx.x;
  const int wg  = blockIdx.x;
  const int b0  = (wg >> 4) * 64;
  const int k0  = (wg & 15) * 16;
  const int gid = (wg << 9) | tid;

  const float* wmax = ws + WS_WMAX/4;
  const uint32_t* keys = (const uint32_t*)((char*)ws + WS_KEYS);
  const float* bias = ws + WS_BIAS/4;
  const float* qw   = ws + WS_QW/4;
  unsigned short* ht = (unsigned short*)((char*)ws + WS_HT);
  float* wn = (float*)((char*)ws + WS_WN);

  __shared__ __align__(16) float achunk[64*64];  // A rows(k) x 64 batch
  __shared__ __align__(16) float wch[64*64];     // W rows(k) x 64 cols
  __shared__ __align__(16) float gsm[64*68];     // gates [m][64 + pad]

  const float wmih = wmax[0], wmhh = wmax[1];
  const int tn = tid & 15, tm = tid >> 4;        // col-thread, row-group
  const int mU = tid & 63, kkU = tid >> 6;       // update-phase ownership

  // per-thread constants
  // bias for cols 4tn..4tn+3 (gate cols: quarter = tn>>2, offset k0 + 4*(tn&3))
  const float4 bb = *(const float4*)&bias[((tn>>2)<<8) + k0 + ((tn&3)<<2)];

  float c_reg[2] = {0.f, 0.f};

  // prologue: noisy weights for t=0
  gen_noise_step(keys + 0, qw, wmih, wmhh, wn, gid);
  grid.sync();

  for (int t = 0; t < TSTEPS; ++t){
    const float* wcur = wn + (size_t)(t & 1) * NNOISE;
    float* wnxt = wn + (size_t)((t + 1) & 1) * NNOISE;
    const unsigned short* hcur = ht + (size_t)(t & 1) * HT_N;
    unsigned short* hnxt = ht + (size_t)((t + 1) & 1) * HT_N;

    // A) pipeline: generate noisy weights for t+1 (VALU)
    if (t + 1 < TSTEPS)
      gen_noise_step(keys + (t+1)*4, qw, wmih, wmhh, wnxt, gid);

    // B) GEMM over K chunks {40(x), 64,64,64,64(h)}
    float acc[2][4];
    acc[0][0]=0.f;acc[0][1]=0.f;acc[0][2]=0.f;acc[0][3]=0.f;
    acc[1][0]=0.f;acc[1][1]=0.f;acc[1][2]=0.f;acc[1][3]=0.f;

    #pragma unroll 1
    for (int ci = 0; ci < 5; ++ci){
      const int c0  = (ci == 0) ? 0 : (40 + 64*(ci-1));
      const int csz = (ci == 0) ? 40 : 64;
      __syncthreads();
      // stage W chunk: [csz][64], coalesced global reads, linear LDS writes
      {
        const int nel = csz * 64;
        for (int el = tid; el < nel; el += 512){
          int r = el >> 6, n = el & 63;
          int col = ((n >> 4) << 8) + k0 + (n & 15);
          wch[el] = wcur[(size_t)(c0 + r)*GATES + col];
        }
      }
      // stage A chunk
      if (ci == 0){
        // x: 64 rows x 40 k, read as flat 2560 f32 (coalesced), quantize
        const float* xsrc = inputs + (size_t)t*BATCH*IDIM + (size_t)b0*IDIM;
        #pragma unroll
        for (int i = 0; i < 5; ++i){
          int el = tid + 512*i;              // el = m*40 + kx
          int m = el / 40, kx = el - m*40;
          achunk[kx*64 + m] = qclip(xsrc[el], 128.0f, 0.0078125f);
        }
      } else {
        // h: 64 rows x 64 m from hT[hid][batch] (bf16 exact), coalesced u16 reads
        const int hbase = c0 - 40;
        #pragma unroll
        for (int i = 0; i < 8; ++i){
          int r = kkU + 8*i;                 // 0..63
          unsigned short hv = hcur[(size_t)(hbase + r)*BATCH + b0 + mU];
          achunk[r*64 + mU] = __uint_as_float((uint32_t)hv << 16);
        }
      }
      __syncthreads();
      // compute: per k: 1 b128 (W) + 1 b64 (A broadcast) + 8 FMA
      #pragma unroll 4
      for (int k = 0; k < csz; ++k){
        const float4 wv = *(const float4*)&wch[k*64 + 4*tn];
        const float2 av = *(const float2*)&achunk[k*64 + 2*tm];
        acc[0][0] = fmaf(av.x, wv.x, acc[0][0]);
        acc[0][1] = fmaf(av.x, wv.y, acc[0][1]);
        acc[0][2] = fmaf(av.x, wv.z, acc[0][2]);
        acc[0][3] = fmaf(av.x, wv.w, acc[0][3]);
        acc[1][0] = fmaf(av.y, wv.x, acc[1][0]);
        acc[1][1] = fmaf(av.y, wv.y, acc[1][1]);
        acc[1][2] = fmaf(av.y, wv.z, acc[1][2]);
        acc[1][3] = fmaf(av.y, wv.w, acc[1][3]);
      }
    }

    // C) gates + bias -> LDS
    {
      float4 g0, g1;
      g0.x = __fadd_rn(acc[0][0], bb.x); g0.y = __fadd_rn(acc[0][1], bb.y);
      g0.z = __fadd_rn(acc[0][2], bb.z); g0.w = __fadd_rn(acc[0][3], bb.w);
      g1.x = __fadd_rn(acc[1][0], bb.x); g1.y = __fadd_rn(acc[1][1], bb.y);
      g1.z = __fadd_rn(acc[1][2], bb.z); g1.w = __fadd_rn(acc[1][3], bb.w);
      *(float4*)&gsm[(2*tm + 0)*68 + 4*tn] = g0;
      *(float4*)&gsm[(2*tm + 1)*68 + 4*tn] = g1;
    }
    __syncthreads();

    // D) state update: thread owns (m=mU, kk=kkU) and (m=mU, kk=kkU+8)
    #pragma unroll
    for (int j = 0; j < 2; ++j){
      int kk = kkU + 8*j;
      float gi = gsm[mU*68 +  0 + kk];
      float gf = gsm[mU*68 + 16 + kk];
      float gg = gsm[mU*68 + 32 + kk];
      float go = gsm[mU*68 + 48 + kk];
      float i_ = qclip(sigmoid_xla(gi), 256.0f, 0.00390625f);
      float f_ = qclip(sigmoid_xla(gf), 256.0f, 0.00390625f);
      float g_ = qclip(tanh_xla(gg),    128.0f, 0.0078125f);
      float o_ = qclip(sigmoid_xla(go), 256.0f, 0.00390625f);
      float cpre = __fadd_rn(__fmul_rn(f_, c_reg[j]), __fmul_rn(i_, g_));
      float cy = qclip(cpre, 128.0f, 0.0078125f);
      float hy = qclip(__fmul_rn(o_, tanh_xla(cy)), 128.0f, 0.0078125f);
      c_reg[j] = cy;
      hnxt[(size_t)(k0 + kk)*BATCH + b0 + mU] = (unsigned short)(__float_as_uint(hy) >> 16);
    }
    grid.sync();
  }

  // epilogue: fc = h_T @ out_w.T + out_b ; out = qclip(sigmoid(fc), 256)
  // final h is in ht buffer 0 ((TSTEPS)&1 == 0). One wave per (o, 64-batch group).
  {
    const unsigned short* hf = ht;
    int wid = gid >> 6, lane = gid & 63;
    if (wid < 192){
      int o = wid % 12, bg = wid / 12;
      int b = bg*64 + lane;
      float s = 0.f;
      for (int k = 0; k < HID; ++k){
        float h = __uint_as_float((uint32_t)hf[(size_t)k*BATCH + b] << 16);
        s = fmaf(h, out_w[o*HID + k], s);
      }
      s = __fadd_rn(s, out_b[o]);
      out[b*ODIM + o] = qclip(sigmoid_xla(s), 256.0f, 0.00390625f);
    }
  }
}

// ======================= launch =======================
extern "C" void kernel_launch(void* const* d_in, const int* in_sizes, int n_in,
                              void* d_out, int out_size, void* d_ws, size_t ws_size,
                              hipStream_t stream){
  const float* inputs = (const float*)d_in[0];
  const float* w_ih   = (const float*)d_in[1];
  const float* w_hh   = (const float*)d_in[2];
  const float* b_ih   = (const float*)d_in[3];
  const float* b_hh   = (const float*)d_in[4];
  const float* out_w  = (const float*)d_in[5];
  const float* out_b  = (const float*)d_in[6];
  float* out = (float*)d_out;
  float* ws  = (float*)d_ws;

  // zero wmax slots + h0 buffer (ws is poisoned 0xAA before every timed launch)
  hipMemsetAsync(d_ws, 0, 8, stream);
  hipMemsetAsync((char*)d_ws + WS_HT, 0, HT_N*sizeof(unsigned short), stream);

  kws_prep<<<dim3(256), dim3(256), 0, stream>>>(w_ih, w_hh, b_ih, b_hh, ws);

  void* args[] = { (void*)&inputs, (void*)&out_w, (void*)&out_b, (void*)&out, (void*)&ws };
  hipLaunchCooperativeKernel((const void*)kws_lstm_coop, dim3(256), dim3(512),
                             args, 0, stream);
}

// Round 7
// 10824.708 us; speedup vs baseline: 1.6136x; 1.3182x over previous
//
#include <hip/hip_runtime.h>
#include <stdint.h>

// ---- problem constants ----
#define IDIM   40
#define HID    256
#define GATES  1024           // 4*HID
#define KTOT   296            // IDIM + HID
#define TSTEPS 256
#define BATCH  1024
#define ODIM   12
#define NNOISE (KTOT*GATES)   // 303104
#define NIH    (IDIM*GATES)   // 40960
#define NWG    256
#define NTHR   1024
#define NTHR_TOTAL (NWG*NTHR) // 262144

// ---- ws layout (byte offsets) ----
#define WS_WMAX  0             // 2 f32 (memset 0)
#define WS_FLAGS 64            // 256 u32 barrier flags (memset 0)
#define WS_KEYS  1088          // 256*4 u32
#define WS_BIAS  5184          // 1024 f32
#define WS_QW    9280          // 303104 f32 [KTOT][1024]
#define WS_HT    1221696       // 2 * 256*1024 u16 (bf16 [hid][batch]); buf0 memset 0
#define WS_WN    2270272       // 2 * 303104 f32 noisy weights (double buffered)
#define HT_N     (HID*BATCH)   // 262144 u16 per buffer

// ======================= threefry2x32 (exact JAX) =======================
__device__ __forceinline__ uint32_t rotl32(uint32_t x, int r){ return (x<<r)|(x>>(32-r)); }

__device__ __forceinline__ void tf2x32(uint32_t k0, uint32_t k1, uint32_t c0, uint32_t c1,
                                       uint32_t &o0, uint32_t &o1){
  uint32_t ks2 = k0 ^ k1 ^ 0x1BD11BDAu;
  uint32_t x0 = c0 + k0, x1 = c1 + k1;
#define R4(a,b,c,d) x0+=x1; x1=rotl32(x1,a); x1^=x0; x0+=x1; x1=rotl32(x1,b); x1^=x0; \
                    x0+=x1; x1=rotl32(x1,c); x1^=x0; x0+=x1; x1=rotl32(x1,d); x1^=x0;
  R4(13,15,26,6)  x0+=k1;  x1+=ks2+1u;
  R4(17,29,16,24) x0+=ks2; x1+=k0+2u;
  R4(13,15,26,6)  x0+=k0;  x1+=k1+3u;
  R4(17,29,16,24) x0+=k1;  x1+=ks2+4u;
  R4(13,15,26,6)  x0+=ks2; x1+=k0+5u;
#undef R4
  o0=x0; o1=x1;
}

// ======================= XLA-faithful math =======================
__device__ __forceinline__ float erfinv_xla(float x){
  float w = -log1pf(-__fmul_rn(x,x));
  float p;
  if (w < 5.0f){
    w = __fsub_rn(w, 2.5f);
    p = 2.81022636e-08f;
    p = __fadd_rn(__fmul_rn(p,w),  3.43273939e-07f);
    p = __fadd_rn(__fmul_rn(p,w), -3.5233877e-06f);
    p = __fadd_rn(__fmul_rn(p,w), -4.39150654e-06f);
    p = __fadd_rn(__fmul_rn(p,w),  0.00021858087f);
    p = __fadd_rn(__fmul_rn(p,w), -0.00125372503f);
    p = __fadd_rn(__fmul_rn(p,w), -0.00417768164f);
    p = __fadd_rn(__fmul_rn(p,w),  0.246640727f);
    p = __fadd_rn(__fmul_rn(p,w),  1.50140941f);
  } else {
    w = __fsub_rn(sqrtf(w), 3.0f);
    p = -0.000200214257f;
    p = __fadd_rn(__fmul_rn(p,w),  0.000100950558f);
    p = __fadd_rn(__fmul_rn(p,w),  0.00134934322f);
    p = __fadd_rn(__fmul_rn(p,w), -0.00367342844f);
    p = __fadd_rn(__fmul_rn(p,w),  0.00573950773f);
    p = __fadd_rn(__fmul_rn(p,w), -0.0076224613f);
    p = __fadd_rn(__fmul_rn(p,w),  0.00943887047f);
    p = __fadd_rn(__fmul_rn(p,w),  1.00167406f);
    p = __fadd_rn(__fmul_rn(p,w),  2.83297682f);
  }
  return __fmul_rn(p, x);
}

__device__ __forceinline__ float tanh_xla(float x){
  float xc = fminf(fmaxf(x, -9.0f), 9.0f);
  float x2 = __fmul_rn(xc, xc);
  float p = -2.76076847742355e-16f;
  p = __fadd_rn(__fmul_rn(p,x2),  2.00018790482477e-13f);
  p = __fadd_rn(__fmul_rn(p,x2), -8.60467152213735e-11f);
  p = __fadd_rn(__fmul_rn(p,x2),  5.12229709037114e-08f);
  p = __fadd_rn(__fmul_rn(p,x2),  1.48572235717979e-05f);
  p = __fadd_rn(__fmul_rn(p,x2),  6.37261928875436e-04f);
  p = __fadd_rn(__fmul_rn(p,x2),  4.89352455891786e-03f);
  float num = __fmul_rn(xc, p);
  float q = 1.19825839466702e-06f;
  q = __fadd_rn(__fmul_rn(q,x2),  1.18534705686654e-04f);
  q = __fadd_rn(__fmul_rn(q,x2),  2.26843463243900e-03f);
  q = __fadd_rn(__fmul_rn(q,x2),  4.89352518554385e-03f);
  float r = __fdiv_rn(num, q);
  return (fabsf(x) < 0.0004f) ? x : r;
}

__device__ __forceinline__ float sigmoid_xla(float x){
  return __fadd_rn(0.5f, __fmul_rn(0.5f, tanh_xla(__fmul_rn(0.5f, x))));
}

__device__ __forceinline__ float qclip(float x, float s, float inv){
  float c = fminf(fmaxf(x, 0.0f), 1.0f);
  float y = __fmul_rn(rintf(__fmul_rn(c, s)), inv);
  return __fadd_rn(x, __fsub_rn(y, x));
}

__device__ __forceinline__ float bits_to_normal(uint32_t bits){
  float f = __fsub_rn(__uint_as_float((bits>>9) | 0x3F800000u), 1.0f);
  const float LO = __uint_as_float(0xBF7FFFFFu);
  float u = fmaxf(LO, __fadd_rn(__fmul_rn(f, 2.0f), LO));
  return __fmul_rn(__uint_as_float(0x3FB504F3u), erfinv_xla(u));
}

__device__ __forceinline__ void gen_noise_step(const uint32_t* kk, const float* qw,
                                               float wmih, float wmhh, float* dst, int gid){
  for (int idx = gid; idx < NNOISE; idx += NTHR_TOTAL){
    bool ih = idx < NIH;
    uint32_t key0 = ih ? kk[0] : kk[2];
    uint32_t key1 = ih ? kk[1] : kk[3];
    uint32_t li   = ih ? (uint32_t)idx : (uint32_t)(idx - NIH);
    uint32_t a,b; tf2x32(key0,key1, 0u, li, a,b);
    uint32_t bits = a ^ b;
    float nv = bits_to_normal(bits);
    float noise = __fmul_rn(__fmul_rn(nv, ih ? wmih : wmhh), 0.1f);
    dst[idx] = __fadd_rn(qw[idx], noise);
  }
}

// ============== flag-array grid barrier (no atomic-RMW serialization) ==============
// Producer: syncthreads (drains all threads' stores) -> tid0: wbL2 fence + flag store.
// Consumer: each of first NWG threads polls one flag (parallel agent-scope loads),
// then one L2-invalidate fence per WG. Requires all WGs co-resident (cooperative).
__device__ __forceinline__ void grid_barrier(uint32_t* flags, int wg, int tid, uint32_t target){
  __syncthreads();
  if (tid == 0){
    __threadfence();   // release: writeback L2 (covers all this XCD's dirty lines)
    __hip_atomic_store(&flags[wg], target, __ATOMIC_RELAXED, __HIP_MEMORY_SCOPE_AGENT);
  }
  if (tid < NWG){
    while (__hip_atomic_load(&flags[tid], __ATOMIC_RELAXED, __HIP_MEMORY_SCOPE_AGENT) < target)
      __builtin_amdgcn_s_sleep(4);
  }
  __syncthreads();
  if (tid == 0) __threadfence();   // acquire: invalidate this XCD's L2
  __syncthreads();
}

// ======================= prep kernel =======================
__global__ void __launch_bounds__(256)
kws_prep(const float* __restrict__ w_ih, const float* __restrict__ w_hh,
         const float* __restrict__ b_ih, const float* __restrict__ b_hh,
         float* __restrict__ ws){
  const int gtid = blockIdx.x*256 + threadIdx.x;
  const int nth  = gridDim.x*256;
  float* wmax = ws + WS_WMAX/4;
  uint32_t* keys = (uint32_t*)((char*)ws + WS_KEYS);
  float* bias = ws + WS_BIAS/4;
  float* qw   = ws + WS_QW/4;

  for (int idx = gtid; idx < NNOISE; idx += nth){
    int r = idx >> 10, j = idx & 1023;
    float w = (r < IDIM) ? w_ih[j*IDIM + r] : w_hh[j*HID + (r-IDIM)];
    qw[idx] = qclip(w, 128.0f, 0.0078125f);
  }
  for (int j = gtid; j < GATES; j += nth)
    bias[j] = __fadd_rn(qclip(b_ih[j],128.0f,0.0078125f), qclip(b_hh[j],128.0f,0.0078125f));
  for (int t = gtid; t < TSTEPS; t += nth){
    uint32_t ka,kb, k1a,k1b,k2a,k2b;
    tf2x32(0u, 42u, 0u, (uint32_t)t, ka, kb);
    tf2x32(ka,kb, 0u,0u, k1a,k1b);
    tf2x32(ka,kb, 0u,1u, k2a,k2b);
    keys[t*4+0]=k1a; keys[t*4+1]=k1b; keys[t*4+2]=k2a; keys[t*4+3]=k2b;
  }
  float m1 = -1e30f, m2 = -1e30f;
  for (int i = gtid; i < GATES*IDIM; i += nth) m1 = fmaxf(m1, w_ih[i]);
  for (int i = gtid; i < GATES*HID;  i += nth) m2 = fmaxf(m2, w_hh[i]);
  for (int off = 32; off; off >>= 1){
    m1 = fmaxf(m1, __shfl_down(m1, off));
    m2 = fmaxf(m2, __shfl_down(m2, off));
  }
  if ((threadIdx.x & 63) == 0){
    if (m1 > 0.f) atomicMax((int*)&wmax[0], __float_as_int(m1));
    if (m2 > 0.f) atomicMax((int*)&wmax[1], __float_as_int(m2));
  }
}

// ======================= cooperative LSTM kernel =======================
// 256 WGs x 1024 thr (16 waves/CU). WG = (64 batch) x (16 hid -> 64 gate cols).
// Thread GEMM tile 2x2; wave footprint 8x8 (tn bits 0-2,6-7; tm bits 3-5,8-9)
// -> 64B W + 64B A distinct LDS bytes per k per wave, conflict-free.
__global__ void __launch_bounds__(1024, 4)
kws_lstm_coop(const float* __restrict__ inputs, const float* __restrict__ out_w,
              const float* __restrict__ out_b, float* __restrict__ out,
              float* __restrict__ ws){
  const int tid = threadIdx.x;
  const int wg  = blockIdx.x;
  const int b0  = (wg >> 4) * 64;
  const int k0  = (wg & 15) * 16;
  const int gid = (wg << 10) | tid;

  const float* wmax = ws + WS_WMAX/4;
  uint32_t* flags = (uint32_t*)((char*)ws + WS_FLAGS);
  const uint32_t* keys = (const uint32_t*)((char*)ws + WS_KEYS);
  const float* bias = ws + WS_BIAS/4;
  const float* qw   = ws + WS_QW/4;
  unsigned short* ht = (unsigned short*)((char*)ws + WS_HT);
  float* wn = (float*)((char*)ws + WS_WN);

  __shared__ __align__(16) float wch[64*64];     // W chunk [k][64 cols]
  __shared__ __align__(16) float achunk[64*68];  // A chunk [k][64 batch + pad]
  __shared__ __align__(16) float gsm[64*68];     // gates [m][64 + pad]

  const float wmih = wmax[0], wmhh = wmax[1];
  // GEMM mapping: 2x2 tile, 8x8 wave footprint
  const int tn = (tid & 7) + ((tid >> 6) & 3) * 8;   // col-group 0..31
  const int tm = ((tid >> 3) & 7) + (tid >> 8) * 8;  // row-group 0..31
  const int mU = tid & 63, kkU = tid >> 6;           // update ownership (1 h/thread)

  // bias for cols n=2tn, 2tn+1 (same gate quarter since n even)
  const int nb = 2*tn;
  const float2 bb = *(const float2*)&bias[((nb >> 4) << 8) + k0 + (nb & 15)];

  float c_reg = 0.f;

  // prologue: noisy weights for t=0
  gen_noise_step(keys + 0, qw, wmih, wmhh, wn, gid);
  grid_barrier(flags, wg, tid, 1u);

  for (int t = 0; t < TSTEPS; ++t){
    const float* wcur = wn + (size_t)(t & 1) * NNOISE;
    float* wnxt = wn + (size_t)((t + 1) & 1) * NNOISE;
    const unsigned short* hcur = ht + (size_t)(t & 1) * HT_N;
    unsigned short* hnxt = ht + (size_t)((t + 1) & 1) * HT_N;

    // A) pipeline: noisy weights for t+1
    if (t + 1 < TSTEPS)
      gen_noise_step(keys + (t+1)*4, qw, wmih, wmhh, wnxt, gid);

    // B) GEMM over K chunks {40(x), 64,64,64,64(h)}
    float acc00=0.f, acc01=0.f, acc10=0.f, acc11=0.f;

    #pragma unroll 1
    for (int ci = 0; ci < 5; ++ci){
      const int c0  = (ci == 0) ? 0 : (40 + 64*(ci-1));
      const int csz = (ci == 0) ? 40 : 64;
      __syncthreads();
      // stage W chunk [csz][64], coalesced reads, linear conflict-free LDS writes
      for (int el = tid; el < csz*64; el += NTHR){
        int r = el >> 6, n = el & 63;
        int col = ((n >> 4) << 8) + k0 + (n & 15);
        wch[el] = wcur[(size_t)(c0 + r)*GATES + col];
      }
      // stage A chunk (f32, [k][batch] stride 68)
      if (ci == 0){
        const float* xsrc = inputs + (size_t)t*BATCH*IDIM + (size_t)b0*IDIM;
        #pragma unroll
        for (int i = 0; i < 3; ++i){
          int el = tid + NTHR*i;             // el = m*40 + kx
          if (el < 64*IDIM){
            int m = el / IDIM, kx = el - m*IDIM;
            achunk[kx*68 + m] = qclip(xsrc[el], 128.0f, 0.0078125f);
          }
        }
      } else {
        const int hbase = c0 - 40;
        int r = tid >> 4, b8 = (tid & 15) * 4;   // 64 rows x 16 groups x 4 u16
        ushort4 hv = *(const ushort4*)&hcur[(size_t)(hbase + r)*BATCH + b0 + b8];
        float4 fv;
        fv.x = __uint_as_float((uint32_t)hv.x << 16);
        fv.y = __uint_as_float((uint32_t)hv.y << 16);
        fv.z = __uint_as_float((uint32_t)hv.z << 16);
        fv.w = __uint_as_float((uint32_t)hv.w << 16);
        *(float4*)&achunk[r*68 + b8] = fv;
      }
      __syncthreads();
      // compute: per k: 2 b64 reads + 4 FMA
      #pragma unroll 4
      for (int k = 0; k < csz; ++k){
        const float2 wv = *(const float2*)&wch[k*64 + 2*tn];
        const float2 av = *(const float2*)&achunk[k*68 + 2*tm];
        acc00 = fmaf(av.x, wv.x, acc00);
        acc01 = fmaf(av.x, wv.y, acc01);
        acc10 = fmaf(av.y, wv.x, acc10);
        acc11 = fmaf(av.y, wv.y, acc11);
      }
    }
    __syncthreads();

    // C) gates + bias -> LDS
    {
      float2 g0, g1;
      g0.x = __fadd_rn(acc00, bb.x); g0.y = __fadd_rn(acc01, bb.y);
      g1.x = __fadd_rn(acc10, bb.x); g1.y = __fadd_rn(acc11, bb.y);
      *(float2*)&gsm[(2*tm + 0)*68 + 2*tn] = g0;
      *(float2*)&gsm[(2*tm + 1)*68 + 2*tn] = g1;
    }
    __syncthreads();

    // D) state update: thread owns (m=mU, hid k0+kkU)
    {
      float gi = gsm[mU*68 +  0 + kkU];
      float gf = gsm[mU*68 + 16 + kkU];
      float gg = gsm[mU*68 + 32 + kkU];
      float go = gsm[mU*68 + 48 + kkU];
      float i_ = qclip(sigmoid_xla(gi), 256.0f, 0.00390625f);
      float f_ = qclip(sigmoid_xla(gf), 256.0f, 0.00390625f);
      float g_ = qclip(tanh_xla(gg),    128.0f, 0.0078125f);
      float o_ = qclip(sigmoid_xla(go), 256.0f, 0.00390625f);
      float cpre = __fadd_rn(__fmul_rn(f_, c_reg), __fmul_rn(i_, g_));
      float cy = qclip(cpre, 128.0f, 0.0078125f);
      float hy = qclip(__fmul_rn(o_, tanh_xla(cy)), 128.0f, 0.0078125f);
      c_reg = cy;
      hnxt[(size_t)(k0 + kkU)*BATCH + b0 + mU] = (unsigned short)(__float_as_uint(hy) >> 16);
    }
    grid_barrier(flags, wg, tid, (uint32_t)(t + 2));
  }

  // epilogue: fc = h_T @ out_w.T + out_b ; out = qclip(sigmoid(fc), 256)
  {
    const unsigned short* hf = ht;   // final h in buffer 0 (TSTEPS even)
    int wid = gid >> 6, lane = gid & 63;
    if (wid < 192){
      int o = wid % 12, bg = wid / 12;
      int b = bg*64 + lane;
      float s = 0.f;
      for (int k = 0; k < HID; ++k){
        float h = __uint_as_float((uint32_t)hf[(size_t)k*BATCH + b] << 16);
        s = fmaf(h, out_w[o*HID + k], s);
      }
      s = __fadd_rn(s, out_b[o]);
      out[b*ODIM + o] = qclip(sigmoid_xla(s), 256.0f, 0.00390625f);
    }
  }
}

// ======================= launch =======================
extern "C" void kernel_launch(void* const* d_in, const int* in_sizes, int n_in,
                              void* d_out, int out_size, void* d_ws, size_t ws_size,
                              hipStream_t stream){
  const float* inputs = (const float*)d_in[0];
  const float* w_ih   = (const float*)d_in[1];
  const float* w_hh   = (const float*)d_in[2];
  const float* b_ih   = (const float*)d_in[3];
  const float* b_hh   = (const float*)d_in[4];
  const float* out_w  = (const float*)d_in[5];
  const float* out_b  = (const float*)d_in[6];
  float* out = (float*)d_out;
  float* ws  = (float*)d_ws;

  // ws is re-poisoned 0xAA before every timed launch: zero what must be zero
  hipMemsetAsync(d_ws, 0, 8, stream);                                      // wmax
  hipMemsetAsync((char*)d_ws + WS_FLAGS, 0, NWG*sizeof(uint32_t), stream); // barrier flags
  hipMemsetAsync((char*)d_ws + WS_HT, 0, HT_N*sizeof(unsigned short), stream); // h0

  kws_prep<<<dim3(256), dim3(256), 0, stream>>>(w_ih, w_hh, b_ih, b_hh, ws);

  void* args[] = { (void*)&inputs, (void*)&out_w, (void*)&out_b, (void*)&out, (void*)&ws };
  hipLaunchCooperativeKernel((const void*)kws_lstm_coop, dim3(NWG), dim3(NTHR),
                             args, 0, stream);
}